// Round 14
// baseline (419.062 us; speedup 1.0000x reference)
//
#include <hip/hip_runtime.h>
#include <hip/hip_bf16.h>
#include <cstdint>
#include <cstddef>

#define GLB(p)  ((const __attribute__((address_space(1))) void*)(p))
#define LDSP(p) ((__attribute__((address_space(3))) void*)(p))

typedef __attribute__((ext_vector_type(8))) __bf16 bf16x8;
typedef __attribute__((ext_vector_type(4))) float  f32x4;
typedef __attribute__((ext_vector_type(8))) unsigned short u16x8;

static constexpr int Mdim = 8192, Ndim = 4096, Kdim = 4096;

#define S_BAR()      do { asm volatile("" ::: "memory"); __builtin_amdgcn_s_barrier(); asm volatile("" ::: "memory"); } while (0)
#define WAIT_LGKM(n) asm volatile("s_waitcnt lgkmcnt(" #n ")" ::: "memory")
#define WAIT_VM(n)   asm volatile("s_waitcnt vmcnt(" #n ")" ::: "memory")

static __device__ __forceinline__ unsigned short f2bf_bits(float f) {
    __hip_bfloat16 h = __float2bfloat16(f);
    return __builtin_bit_cast(unsigned short, h);
}

// swizzle: involution on byte offsets within a 16 KiB slot.
// XOR byte bits 4-6 with row bits 0-2 (row = 128-byte line).  [G4 st-style]
static __device__ __forceinline__ int swz16k(int p) {
    return p ^ (((p >> 7) & 7) << 4);
}

// ---------------------------------------------------------------------------
// Fused preproc (r7, verified, HBM-roofline): X row-L2norm->bf16 + W->bf16.
// ---------------------------------------------------------------------------
__global__ void __launch_bounds__(256) preproc_kernel(const float* __restrict__ x,
                                                      const float* __restrict__ Wf,
                                                      __hip_bfloat16* __restrict__ xn,
                                                      __hip_bfloat16* __restrict__ Wb)
{
    const int row = blockIdx.x;
    const int t = threadIdx.x;

    const float4* xr = (const float4*)(x + (size_t)row * Kdim);
    float4 v[4];
    float s = 0.f;
#pragma unroll
    for (int i = 0; i < 4; ++i) {
        v[i] = xr[i * 256 + t];
        s += v[i].x * v[i].x + v[i].y * v[i].y + v[i].z * v[i].z + v[i].w * v[i].w;
    }
#pragma unroll
    for (int off = 32; off > 0; off >>= 1) s += __shfl_down(s, off, 64);
    __shared__ float red[4];
    const int lane = t & 63, w = t >> 6;
    if (lane == 0) red[w] = s;
    __syncthreads();
    const float tot = red[0] + red[1] + red[2] + red[3];
    const float inv = 1.f / (sqrtf(tot) + 1e-8f);
    ushort4* xo = (ushort4*)(xn + (size_t)row * Kdim);
#pragma unroll
    for (int i = 0; i < 4; ++i) {
        ushort4 o;
        o.x = f2bf_bits(v[i].x * inv);
        o.y = f2bf_bits(v[i].y * inv);
        o.z = f2bf_bits(v[i].z * inv);
        o.w = f2bf_bits(v[i].w * inv);
        xo[i * 256 + t] = o;
    }

    const size_t idx = (size_t)row * 256 + t;
    const float4* p = (const float4*)Wf + idx * 2;
    const float4 a = p[0], c = p[1];
    u16x8 o;
    o[0] = f2bf_bits(a.x); o[1] = f2bf_bits(a.y);
    o[2] = f2bf_bits(a.z); o[3] = f2bf_bits(a.w);
    o[4] = f2bf_bits(c.x); o[5] = f2bf_bits(c.y);
    o[6] = f2bf_bits(c.z); o[7] = f2bf_bits(c.w);
    *((u16x8*)Wb + idx) = o;
}

// ---------------------------------------------------------------------------
// GEMM r14 = r13 + Bg row fix: wave wn's B rows are n0 + wn*64 + j*16 + fr
// (r13 dropped the (wn>>1)*128 slot-half term -> waves 2,3 read wrong rows).
// Structure: r10's A-side (A-only 4-slot 64 KiB ring, 3-bit swizzle,
// ping-pong, 2 barriers/K-tile) + B direct global->reg, prefetched one
// K-tile ahead (bf0/bf1 named sets, loop unrolled x2, rule #20).
// Mechanism: LDS pipe 2816 -> ~1800 cyc/tile (reads 24->16/wave, writes
// halved); MFMA (2483) becomes the clear critical pipe.  B panel (2 MB) is
// L2-resident; per-row 64B segments; ~4600 cyc prefetch flight.
// vmcnt ledger/tile: [B(t+1)x8 @head][A(t+2)x4 @tail]; boundary WAIT_VM(4)
// lands A(t+1)+B(t+1), keeps A(t+2) in flight.
// ---------------------------------------------------------------------------
__global__ void __launch_bounds__(512, 2) gemm256_bd(
        const __hip_bfloat16* __restrict__ A,   // [M][K]
        const __hip_bfloat16* __restrict__ B,   // [N][K]
        const float* __restrict__ bias,         // [N]
        float* __restrict__ out)                // [M][N]
{
    constexpr int NT  = Kdim / 64;             // 64 K-tiles (even)
    constexpr int NTN = Ndim / 256;            // 16
    constexpr int NWG = (Mdim / 256) * NTN;    // 512 (%8==0)
    extern __shared__ char smem[];             // 64 KiB (A ring only)

    const int bid = blockIdx.x;
    const int swz = (bid & 7) * (NWG / 8) + (bid >> 3);
    const int m0 = (swz / NTN) * 256;
    const int n0 = (swz % NTN) * 256;

    const int tid  = threadIdx.x;
    const int lane = tid & 63;
    const int w    = tid >> 6;
    const int wm   = w >> 2;                   // 0..1
    const int wn   = w & 3;                    // 0..3
    const int fr   = lane & 15;
    const int ko2  = (lane >> 4) * 16;         // lane k-offset, bytes
    const int xm   = (lane & 7) << 4;          // read-side swizzle mask

    const int p0 = tid * 16;
    const int p1 = 8192 + tid * 16;
    const int q0 = swz16k(p0);
    const int q1 = swz16k(p1);
    const int sr0 = q0 >> 7, sc0 = (q0 & 127) >> 1;
    const int sr1 = q1 >> 7, sc1 = (q1 & 127) >> 1;

    const __hip_bfloat16* Ab0 = A + (size_t)(m0 + sr0) * Kdim + sc0;
    const __hip_bfloat16* Ab1 = A + (size_t)(m0 + sr1) * Kdim + sc1;
    // per-lane B global base: row = n0 + wn*64 + fr, k = (lane>>4)*8
    // (r13 bug: omitted the (wn>>1)*128 component of wn*64)
    const __hip_bfloat16* Bg = B + (size_t)(n0 + wn * 64 + fr) * Kdim + ((lane >> 4) * 8);

#define STAGE_A(tt, h) do { \
        char* ld_ = smem + ((2 * (tt) + (h)) & 3) * 16384; \
        __builtin_amdgcn_global_load_lds(GLB(Ab0 + (size_t)(h) * (128 * Kdim) + (tt) * 64), LDSP(ld_ + p0), 16, 0, 0); \
        __builtin_amdgcn_global_load_lds(GLB(Ab1 + (size_t)(h) * (128 * Kdim) + (tt) * 64), LDSP(ld_ + p1), 16, 0, 0); \
    } while (0)

#define B_LOAD(dst, tt) do { \
    _Pragma("unroll") for (int j = 0; j < 4; ++j) { \
        dst[j][0] = *(const bf16x8*)(Bg + (size_t)j * (16 * Kdim) + (tt) * 64); \
        dst[j][1] = *(const bf16x8*)(Bg + (size_t)j * (16 * Kdim) + (tt) * 64 + 32); \
    } } while (0)

#define LDS_RD(base, row, kb) (*(const bf16x8*)(smem + ((((base) + (row) * 128 + (kb))) ^ xm)))

#define A_RD(buf, m) do { \
        buf[0] = LDS_RD(sa, (m) * 16 + fr, ko2); \
        buf[1] = LDS_RD(sa, (m) * 16 + fr, 64 + ko2); } while (0)

#define MFMA8(m, abuf, bset) do { \
    __builtin_amdgcn_s_setprio(1); \
    _Pragma("unroll") for (int kk = 0; kk < 2; ++kk) \
    _Pragma("unroll") for (int j = 0; j < 4; ++j) \
        acc[(m)][j] = __builtin_amdgcn_mfma_f32_16x16x32_bf16(abuf[kk], bset[j][kk], acc[(m)][j], 0, 0, 0); \
    __builtin_amdgcn_s_setprio(0); } while (0)

// one K-tile: consume bcur, prefetch bnext = B(t+1)
#define TILE_BODY(t, bcur, bnext) do { \
        const int sa = ((2 * (t) + wm) & 3) * 16384; \
        const int ta = ((t) + 2) & (NT - 1); \
        B_LOAD(bnext, ((t) + 1) & (NT - 1)); \
        A_RD(aA, 0); \
        A_RD(aB, 1); MFMA8(0, aA, bcur); \
        A_RD(aA, 2); MFMA8(1, aB, bcur); \
        A_RD(aB, 3); MFMA8(2, aA, bcur); \
        A_RD(aA, 4); MFMA8(3, aB, bcur); \
        A_RD(aB, 5); MFMA8(4, aA, bcur); \
        A_RD(aA, 6); MFMA8(5, aB, bcur); \
        A_RD(aB, 7); MFMA8(6, aA, bcur); \
        WAIT_LGKM(0); \
        S_BAR();                               /* all waves' tile-t A reads done */ \
        STAGE_A(ta, 0); STAGE_A(ta, 1); \
        MFMA8(7, aB, bcur); \
        WAIT_VM(4);                            /* lands A(t+1)+B(t+1); A(t+2) in flight */ \
        S_BAR(); \
    } while (0)

    f32x4 acc[8][4];
#pragma unroll
    for (int i = 0; i < 8; ++i)
#pragma unroll
        for (int j = 0; j < 4; ++j) acc[i][j] = (f32x4){0.f, 0.f, 0.f, 0.f};

    bf16x8 aA[2], aB[2], bf0[4][2], bf1[4][2];

    // prologue: B(0)x8 regs + A(0)x4 + A(1)x4; vmcnt(4) lands B(0)+A(0),
    // leaves A(1)x4 in flight — steady-state entry ledger.
    B_LOAD(bf0, 0);
    STAGE_A(0, 0); STAGE_A(0, 1);
    STAGE_A(1, 0); STAGE_A(1, 1);
    WAIT_VM(4);
    S_BAR();

    for (int t = 0; t < NT; t += 2) {
        TILE_BODY(t,     bf0, bf1);
        TILE_BODY(t + 1, bf1, bf0);
    }
    WAIT_VM(0);

#undef STAGE_A
#undef B_LOAD
#undef LDS_RD
#undef A_RD
#undef MFMA8
#undef TILE_BODY

    // Epilogue: C/D layout col = lane&15, row = (lane>>4)*4 + q
    const int cl = lane & 15;
    const int rl = (lane >> 4) * 4;
#pragma unroll
    for (int j = 0; j < 4; ++j) {
        const int col = n0 + wn * 64 + j * 16 + cl;
        const float bv = bias[col];
#pragma unroll
        for (int i = 0; i < 8; ++i) {
            const int row = m0 + wm * 128 + i * 16 + rl;
            float* po = out + (size_t)row * Ndim + col;
#pragma unroll
            for (int q = 0; q < 4; ++q) {
                const float r = acc[i][j][q] + bv;
                po[(size_t)q * Ndim] = r > 0.f ? r : 0.f;
            }
        }
    }
}

// ---------------------------------------------------------------------------
// Fallback: r1's verified 128x128 m97-structure GEMM.
// ---------------------------------------------------------------------------
__global__ void __launch_bounds__(256) gemm_bias_relu_kernel(
        const __hip_bfloat16* __restrict__ A,
        const __hip_bfloat16* __restrict__ B,
        const float* __restrict__ bias,
        float* __restrict__ out)
{
    constexpr int BM = 128, BN = 128, BK = 32;
    constexpr int NT_N = Ndim / BN;
    constexpr int NWG  = (Mdim / BM) * NT_N;

    __shared__ __bf16 As[BM * BK];
    __shared__ __bf16 Bs[BN * BK];

    const int bid = blockIdx.x;
    const int swz = (bid & 7) * (NWG / 8) + (bid >> 3);
    const int by = swz / NT_N, bx = swz % NT_N;
    const int m0 = by * BM, n0 = bx * BN;

    const int tid  = threadIdx.x;
    const int lane = tid & 63;
    const int w    = tid >> 6;
    const int wm   = w >> 1, wn = w & 1;

    const int o0 = w * 1024 + lane * 16;
    const int o1 = o0 + 4096;
    const int r0 = o0 >> 6, e0 = (o0 & 63) >> 1;
    const int r1 = o1 >> 6, e1 = (o1 & 63) >> 1;

    const __hip_bfloat16* a0 = A + (size_t)(m0 + r0) * Kdim + e0;
    const __hip_bfloat16* a1 = A + (size_t)(m0 + r1) * Kdim + e1;
    const __hip_bfloat16* b0 = B + (size_t)(n0 + r0) * Kdim + e0;
    const __hip_bfloat16* b1 = B + (size_t)(n0 + r1) * Kdim + e1;
    __bf16* lA0 = As + (o0 >> 1);
    __bf16* lA1 = As + (o1 >> 1);
    __bf16* lB0 = Bs + (o0 >> 1);
    __bf16* lB1 = Bs + (o1 >> 1);

    f32x4 acc[4][4];
#pragma unroll
    for (int i = 0; i < 4; ++i)
#pragma unroll
        for (int j = 0; j < 4; ++j) acc[i][j] = (f32x4){0.f, 0.f, 0.f, 0.f};

    const int fr = lane & 15;
    const int ko = (lane >> 4) * 8;

    for (int kt = 0; kt < Kdim; kt += BK) {
        __builtin_amdgcn_global_load_lds(GLB(a0 + kt), LDSP(lA0), 16, 0, 0);
        __builtin_amdgcn_global_load_lds(GLB(a1 + kt), LDSP(lA1), 16, 0, 0);
        __builtin_amdgcn_global_load_lds(GLB(b0 + kt), LDSP(lB0), 16, 0, 0);
        __builtin_amdgcn_global_load_lds(GLB(b1 + kt), LDSP(lB1), 16, 0, 0);
        __syncthreads();

        bf16x8 af[4], bfr[4];
#pragma unroll
        for (int i = 0; i < 4; ++i)
            af[i]  = *(const bf16x8*)&As[(wm * 64 + i * 16 + fr) * BK + ko];
#pragma unroll
        for (int j = 0; j < 4; ++j)
            bfr[j] = *(const bf16x8*)&Bs[(wn * 64 + j * 16 + fr) * BK + ko];

#pragma unroll
        for (int i = 0; i < 4; ++i)
#pragma unroll
            for (int j = 0; j < 4; ++j)
                acc[i][j] = __builtin_amdgcn_mfma_f32_16x16x32_bf16(af[i], bfr[j], acc[i][j], 0, 0, 0);
        __syncthreads();
    }

    const int cl = lane & 15;
    const int rl = (lane >> 4) * 4;
#pragma unroll
    for (int j = 0; j < 4; ++j) {
        const int col = n0 + wn * 64 + j * 16 + cl;
        const float bv = bias[col];
#pragma unroll
        for (int i = 0; i < 4; ++i) {
            const int row = m0 + wm * 64 + i * 16 + rl;
            float* po = out + (size_t)row * Ndim + col;
#pragma unroll
            for (int q = 0; q < 4; ++q) {
                const float r = acc[i][j][q] + bv;
                po[(size_t)q * Ndim] = r > 0.f ? r : 0.f;
            }
        }
    }
}

// ---------------------------------------------------------------------------
// fp32 fallback path (tiny ws)
// ---------------------------------------------------------------------------
__global__ void __launch_bounds__(256) rownorm_only_kernel(const float* __restrict__ x,
                                                           float* __restrict__ invn)
{
    const int row = blockIdx.x;
    const int t = threadIdx.x;
    const float4* xr = (const float4*)(x + (size_t)row * Kdim);
    float s = 0.f;
#pragma unroll
    for (int i = 0; i < 4; ++i) {
        const float4 v = xr[i * 256 + t];
        s += v.x * v.x + v.y * v.y + v.z * v.z + v.w * v.w;
    }
#pragma unroll
    for (int off = 32; off > 0; off >>= 1) s += __shfl_down(s, off, 64);
    __shared__ float red[4];
    if ((t & 63) == 0) red[t >> 6] = s;
    __syncthreads();
    if (t == 0) {
        const float tot = red[0] + red[1] + red[2] + red[3];
        invn[row] = 1.f / (sqrtf(tot) + 1e-8f);
    }
}

__global__ void __launch_bounds__(256) fallback_gemm_kernel(
        const float* __restrict__ x, const float* __restrict__ W,
        const float* __restrict__ b, const float* __restrict__ invn,
        float* __restrict__ out)
{
    __shared__ float At[16][17], Bt[16][17];
    const int tx = threadIdx.x & 15, ty = threadIdx.x >> 4;
    const int m = blockIdx.y * 16 + ty;
    const int n = blockIdx.x * 16 + tx;
    float s = 0.f;
    for (int k0 = 0; k0 < Kdim; k0 += 16) {
        At[ty][tx] = x[(size_t)m * Kdim + k0 + tx];
        Bt[ty][tx] = W[(size_t)(blockIdx.x * 16 + ty) * Kdim + k0 + tx];
        __syncthreads();
#pragma unroll
        for (int kk = 0; kk < 16; ++kk) s += At[ty][kk] * Bt[tx][kk];
        __syncthreads();
    }
    s = s * invn[m] + b[n];
    out[(size_t)m * Ndim + n] = s > 0.f ? s : 0.f;
}

// ---------------------------------------------------------------------------
extern "C" void kernel_launch(void* const* d_in, const int* in_sizes, int n_in,
                              void* d_out, int out_size, void* d_ws, size_t ws_size,
                              hipStream_t stream)
{
    (void)in_sizes; (void)n_in; (void)out_size;
    const float* x = (const float*)d_in[0];
    const float* W = (const float*)d_in[1];
    const float* b = (const float*)d_in[2];
    float* out = (float*)d_out;

    const size_t needA = (size_t)Mdim * Kdim * sizeof(__hip_bfloat16);   // 64 MB
    const size_t needW = (size_t)Ndim * Kdim * sizeof(__hip_bfloat16);   // 32 MB

    if (ws_size >= needA + needW) {
        __hip_bfloat16* Xn = (__hip_bfloat16*)d_ws;
        __hip_bfloat16* Wb = (__hip_bfloat16*)((char*)d_ws + needA);
        preproc_kernel<<<Mdim, 256, 0, stream>>>(x, W, Xn, Wb);

        hipError_t e = hipFuncSetAttribute((const void*)gemm256_bd,
                                           hipFuncAttributeMaxDynamicSharedMemorySize,
                                           65536);
        if (e == hipSuccess) {
            gemm256_bd<<<(Mdim / 256) * (Ndim / 256), 512, 65536, stream>>>(Xn, Wb, b, out);
        } else {
            gemm_bias_relu_kernel<<<(Mdim / 128) * (Ndim / 128), 256, 0, stream>>>(Xn, Wb, b, out);
        }
    } else {
        float* invn = (float*)d_ws;
        rownorm_only_kernel<<<Mdim, 256, 0, stream>>>(x, invn);
        dim3 g(Ndim / 16, Mdim / 16);
        fallback_gemm_kernel<<<g, 256, 0, stream>>>(x, W, b, invn, out);
    }
}

// Round 15
// 282.696 us; speedup vs baseline: 1.4824x; 1.4824x over previous
//
#include <hip/hip_runtime.h>
#include <hip/hip_bf16.h>
#include <cstdint>
#include <cstddef>

#define GLB(p)  ((const __attribute__((address_space(1))) void*)(p))
#define LDSP(p) ((__attribute__((address_space(3))) void*)(p))

typedef __attribute__((ext_vector_type(8))) __bf16 bf16x8;
typedef __attribute__((ext_vector_type(4))) float  f32x4;
typedef __attribute__((ext_vector_type(8))) unsigned short u16x8;

static constexpr int Mdim = 8192, Ndim = 4096, Kdim = 4096;

#define S_BAR()      do { asm volatile("" ::: "memory"); __builtin_amdgcn_s_barrier(); asm volatile("" ::: "memory"); } while (0)
#define WAIT_LGKM(n) asm volatile("s_waitcnt lgkmcnt(" #n ")" ::: "memory")
#define WAIT_VM(n)   asm volatile("s_waitcnt vmcnt(" #n ")" ::: "memory")

static __device__ __forceinline__ unsigned short f2bf_bits(float f) {
    __hip_bfloat16 h = __float2bfloat16(f);
    return __builtin_bit_cast(unsigned short, h);
}

// swizzle: involution on byte offsets within a 16 KiB slot.
// XOR byte bits 4-6 with row bits 0-2 (row = 128-byte line).  [G4 st-style]
static __device__ __forceinline__ int swz16k(int p) {
    return p ^ (((p >> 7) & 7) << 4);
}

// ---------------------------------------------------------------------------
// Fused preproc (r7, verified, HBM-roofline): X row-L2norm->bf16 + W->bf16.
// ---------------------------------------------------------------------------
__global__ void __launch_bounds__(256) preproc_kernel(const float* __restrict__ x,
                                                      const float* __restrict__ Wf,
                                                      __hip_bfloat16* __restrict__ xn,
                                                      __hip_bfloat16* __restrict__ Wb)
{
    const int row = blockIdx.x;
    const int t = threadIdx.x;

    const float4* xr = (const float4*)(x + (size_t)row * Kdim);
    float4 v[4];
    float s = 0.f;
#pragma unroll
    for (int i = 0; i < 4; ++i) {
        v[i] = xr[i * 256 + t];
        s += v[i].x * v[i].x + v[i].y * v[i].y + v[i].z * v[i].z + v[i].w * v[i].w;
    }
#pragma unroll
    for (int off = 32; off > 0; off >>= 1) s += __shfl_down(s, off, 64);
    __shared__ float red[4];
    const int lane = t & 63, w = t >> 6;
    if (lane == 0) red[w] = s;
    __syncthreads();
    const float tot = red[0] + red[1] + red[2] + red[3];
    const float inv = 1.f / (sqrtf(tot) + 1e-8f);
    ushort4* xo = (ushort4*)(xn + (size_t)row * Kdim);
#pragma unroll
    for (int i = 0; i < 4; ++i) {
        ushort4 o;
        o.x = f2bf_bits(v[i].x * inv);
        o.y = f2bf_bits(v[i].y * inv);
        o.z = f2bf_bits(v[i].z * inv);
        o.w = f2bf_bits(v[i].w * inv);
        xo[i * 256 + t] = o;
    }

    const size_t idx = (size_t)row * 256 + t;
    const float4* p = (const float4*)Wf + idx * 2;
    const float4 a = p[0], c = p[1];
    u16x8 o;
    o[0] = f2bf_bits(a.x); o[1] = f2bf_bits(a.y);
    o[2] = f2bf_bits(a.z); o[3] = f2bf_bits(a.w);
    o[4] = f2bf_bits(c.x); o[5] = f2bf_bits(c.y);
    o[6] = f2bf_bits(c.z); o[7] = f2bf_bits(c.w);
    *((u16x8*)Wb + idx) = o;
}

// ---------------------------------------------------------------------------
// GEMM (r10/r12, best verified: 246 us GEMM, MfmaUtil ~50, conflicts 0,
// reproduced 3x within ±1 us):
// 256x256 tile, 8 waves 2Mx4N (wave-tile 128x64), BK=64, 128 KiB LDS as
// 4 A-slots + 4 B-slots (16 KiB), slot(tile,half)=(2t+h)&3, 3-bit bank
// swizzle both-sides, hold-B-iterate-A (24 b128/tile, zero re-reads),
// explicit A ping-pong, 2 barriers/K-tile, boundary vmcnt(4).
// Design-space bracket (r3-r14): per-phase barriers 261; stage spreading
// 267; 16-wave 335 (LDS-BW-bound, reuse halved); 32x32 MFMA 262 (bank
// conflicts 2.5e7); extra held frags = spill (r6); B-direct-from-global
// 395 (16-segment gather per load — LDS staging IS the transpose).
// Hazard audit:
//   STAGE_B(t+1,*)@head -> targets B(t-1) slots, certified by boundary barrier.
//   STAGE_A(t+2,*)      -> after mid lgkm(0)+barrier (all tile-t reads done;
//                          targets tile-t's own A slots).
//   boundary vmcnt(4)   -> ledger [A(t+1)x4, B(t+1)x4, A(t+2)x4]; lands
//                          exactly tile t+1, A(t+2) stays in flight.
// ---------------------------------------------------------------------------
__global__ void __launch_bounds__(512, 2) gemm256_8p(
        const __hip_bfloat16* __restrict__ A,   // [M][K]
        const __hip_bfloat16* __restrict__ B,   // [N][K]
        const float* __restrict__ bias,         // [N]
        float* __restrict__ out)                // [M][N]
{
    constexpr int NT  = Kdim / 64;             // 64 K-tiles
    constexpr int NTN = Ndim / 256;            // 16
    constexpr int NWG = (Mdim / 256) * NTN;    // 512 (%8==0)
    extern __shared__ char smem[];             // 128 KiB

    const int bid = blockIdx.x;
    const int swz = (bid & 7) * (NWG / 8) + (bid >> 3);
    const int m0 = (swz / NTN) * 256;
    const int n0 = (swz % NTN) * 256;

    const int tid  = threadIdx.x;
    const int lane = tid & 63;
    const int w    = tid >> 6;
    const int wm   = w >> 2;                   // 0..1
    const int wn   = w & 3;                    // 0..3
    const int fr   = lane & 15;
    const int ko2  = (lane >> 4) * 16;         // lane k-offset, bytes
    const int xm   = (lane & 7) << 4;          // read-side swizzle mask
    const int brow = (wn & 1) * 64;

    const int p0 = tid * 16;
    const int p1 = 8192 + tid * 16;
    const int q0 = swz16k(p0);
    const int q1 = swz16k(p1);
    const int sr0 = q0 >> 7, sc0 = (q0 & 127) >> 1;
    const int sr1 = q1 >> 7, sc1 = (q1 & 127) >> 1;

    const __hip_bfloat16* Ab0 = A + (size_t)(m0 + sr0) * Kdim + sc0;
    const __hip_bfloat16* Ab1 = A + (size_t)(m0 + sr1) * Kdim + sc1;
    const __hip_bfloat16* Bb0 = B + (size_t)(n0 + sr0) * Kdim + sc0;
    const __hip_bfloat16* Bb1 = B + (size_t)(n0 + sr1) * Kdim + sc1;

#define STAGE_A(tt, h) do { \
        char* ld_ = smem + ((2 * (tt) + (h)) & 3) * 16384; \
        __builtin_amdgcn_global_load_lds(GLB(Ab0 + (size_t)(h) * (128 * Kdim) + (tt) * 64), LDSP(ld_ + p0), 16, 0, 0); \
        __builtin_amdgcn_global_load_lds(GLB(Ab1 + (size_t)(h) * (128 * Kdim) + (tt) * 64), LDSP(ld_ + p1), 16, 0, 0); \
    } while (0)
#define STAGE_B(tt, h) do { \
        char* ld_ = smem + 65536 + ((2 * (tt) + (h)) & 3) * 16384; \
        __builtin_amdgcn_global_load_lds(GLB(Bb0 + (size_t)(h) * (128 * Kdim) + (tt) * 64), LDSP(ld_ + p0), 16, 0, 0); \
        __builtin_amdgcn_global_load_lds(GLB(Bb1 + (size_t)(h) * (128 * Kdim) + (tt) * 64), LDSP(ld_ + p1), 16, 0, 0); \
    } while (0)

#define LDS_RD(base, row, kb) (*(const bf16x8*)(smem + ((((base) + (row) * 128 + (kb))) ^ xm)))

#define A_RD(buf, m) do { \
        buf[0] = LDS_RD(sa, (m) * 16 + fr, ko2); \
        buf[1] = LDS_RD(sa, (m) * 16 + fr, 64 + ko2); } while (0)

#define MFMA8(m, buf) do { \
    __builtin_amdgcn_s_setprio(1); \
    _Pragma("unroll") for (int kk = 0; kk < 2; ++kk) \
    _Pragma("unroll") for (int j = 0; j < 4; ++j) \
        acc[(m)][j] = __builtin_amdgcn_mfma_f32_16x16x32_bf16(buf[kk], bfr[j][kk], acc[(m)][j], 0, 0, 0); \
    __builtin_amdgcn_s_setprio(0); } while (0)

    f32x4 acc[8][4];
#pragma unroll
    for (int i = 0; i < 8; ++i)
#pragma unroll
        for (int j = 0; j < 4; ++j) acc[i][j] = (f32x4){0.f, 0.f, 0.f, 0.f};

    bf16x8 aA[2], aB[2], bfr[4][2];

    // prologue: tile0 (8 loads) + A(1) (4 loads); vmcnt(4) lands tile0,
    // leaves A(1)x4 in flight — the steady-state entry ledger.
    STAGE_A(0, 0); STAGE_A(0, 1); STAGE_B(0, 0); STAGE_B(0, 1);
    STAGE_A(1, 0); STAGE_A(1, 1);
    WAIT_VM(4);
    S_BAR();

#pragma unroll 2
    for (int t = 0; t < NT; ++t) {
        const int sa = ((2 * t + wm) & 3) * 16384;
        const int sb = 65536 + ((2 * t + (wn >> 1)) & 3) * 16384;
        const int tb = (t + 1) & (NT - 1);     // wraps harmlessly at tail
        const int ta = (t + 2) & (NT - 1);

        // ---- head: read all B n-frags (8 b128), stage B(t+1,0/1),
        //      prime A ping-pong with m0
#pragma unroll
        for (int j = 0; j < 4; ++j) {
            bfr[j][0] = LDS_RD(sb, brow + j * 16 + fr, ko2);
            bfr[j][1] = LDS_RD(sb, brow + j * 16 + fr, 64 + ko2);
        }
        A_RD(aA, 0);
        STAGE_B(tb, 0); STAGE_B(tb, 1);

        // ---- ping-pong: read m+1 into idle buf, MFMA m from live buf
        A_RD(aB, 1); MFMA8(0, aA);
        A_RD(aA, 2); MFMA8(1, aB);
        A_RD(aB, 3); MFMA8(2, aA);
        A_RD(aA, 4); MFMA8(3, aB);
        A_RD(aB, 5); MFMA8(4, aA);
        A_RD(aA, 6); MFMA8(5, aB);
        A_RD(aB, 7); MFMA8(6, aA);

        // ---- tail: all tile-t A reads issued -> certify + stage A(t+2)
        WAIT_LGKM(0);
        S_BAR();                               // all waves' tile-t reads done
        STAGE_A(ta, 0); STAGE_A(ta, 1);
        MFMA8(7, aB);
        WAIT_VM(4);                            // lands tile t+1 exactly
        S_BAR();
    }
    WAIT_VM(0);

#undef STAGE_A
#undef STAGE_B
#undef LDS_RD
#undef A_RD
#undef MFMA8

    // Epilogue: C/D layout col = lane&15, row = (lane>>4)*4 + q
    const int cl = lane & 15;
    const int rl = (lane >> 4) * 4;
#pragma unroll
    for (int j = 0; j < 4; ++j) {
        const int col = n0 + wn * 64 + j * 16 + cl;
        const float bv = bias[col];
#pragma unroll
        for (int i = 0; i < 8; ++i) {
            const int row = m0 + wm * 128 + i * 16 + rl;
            float* po = out + (size_t)row * Ndim + col;
#pragma unroll
            for (int q = 0; q < 4; ++q) {
                const float r = acc[i][j][q] + bv;
                po[(size_t)q * Ndim] = r > 0.f ? r : 0.f;
            }
        }
    }
}

// ---------------------------------------------------------------------------
// Fallback: r1's verified 128x128 m97-structure GEMM.
// ---------------------------------------------------------------------------
__global__ void __launch_bounds__(256) gemm_bias_relu_kernel(
        const __hip_bfloat16* __restrict__ A,
        const __hip_bfloat16* __restrict__ B,
        const float* __restrict__ bias,
        float* __restrict__ out)
{
    constexpr int BM = 128, BN = 128, BK = 32;
    constexpr int NT_N = Ndim / BN;
    constexpr int NWG  = (Mdim / BM) * NT_N;

    __shared__ __bf16 As[BM * BK];
    __shared__ __bf16 Bs[BN * BK];

    const int bid = blockIdx.x;
    const int swz = (bid & 7) * (NWG / 8) + (bid >> 3);
    const int by = swz / NT_N, bx = swz % NT_N;
    const int m0 = by * BM, n0 = bx * BN;

    const int tid  = threadIdx.x;
    const int lane = tid & 63;
    const int w    = tid >> 6;
    const int wm   = w >> 1, wn = w & 1;

    const int o0 = w * 1024 + lane * 16;
    const int o1 = o0 + 4096;
    const int r0 = o0 >> 6, e0 = (o0 & 63) >> 1;
    const int r1 = o1 >> 6, e1 = (o1 & 63) >> 1;

    const __hip_bfloat16* a0 = A + (size_t)(m0 + r0) * Kdim + e0;
    const __hip_bfloat16* a1 = A + (size_t)(m0 + r1) * Kdim + e1;
    const __hip_bfloat16* b0 = B + (size_t)(n0 + r0) * Kdim + e0;
    const __hip_bfloat16* b1 = B + (size_t)(n0 + r1) * Kdim + e1;
    __bf16* lA0 = As + (o0 >> 1);
    __bf16* lA1 = As + (o1 >> 1);
    __bf16* lB0 = Bs + (o0 >> 1);
    __bf16* lB1 = Bs + (o1 >> 1);

    f32x4 acc[4][4];
#pragma unroll
    for (int i = 0; i < 4; ++i)
#pragma unroll
        for (int j = 0; j < 4; ++j) acc[i][j] = (f32x4){0.f, 0.f, 0.f, 0.f};

    const int fr = lane & 15;
    const int ko = (lane >> 4) * 8;

    for (int kt = 0; kt < Kdim; kt += BK) {
        __builtin_amdgcn_global_load_lds(GLB(a0 + kt), LDSP(lA0), 16, 0, 0);
        __builtin_amdgcn_global_load_lds(GLB(a1 + kt), LDSP(lA1), 16, 0, 0);
        __builtin_amdgcn_global_load_lds(GLB(b0 + kt), LDSP(lB0), 16, 0, 0);
        __builtin_amdgcn_global_load_lds(GLB(b1 + kt), LDSP(lB1), 16, 0, 0);
        __syncthreads();

        bf16x8 af[4], bfr[4];
#pragma unroll
        for (int i = 0; i < 4; ++i)
            af[i]  = *(const bf16x8*)&As[(wm * 64 + i * 16 + fr) * BK + ko];
#pragma unroll
        for (int j = 0; j < 4; ++j)
            bfr[j] = *(const bf16x8*)&Bs[(wn * 64 + j * 16 + fr) * BK + ko];

#pragma unroll
        for (int i = 0; i < 4; ++i)
#pragma unroll
            for (int j = 0; j < 4; ++j)
                acc[i][j] = __builtin_amdgcn_mfma_f32_16x16x32_bf16(af[i], bfr[j], acc[i][j], 0, 0, 0);
        __syncthreads();
    }

    const int cl = lane & 15;
    const int rl = (lane >> 4) * 4;
#pragma unroll
    for (int j = 0; j < 4; ++j) {
        const int col = n0 + wn * 64 + j * 16 + cl;
        const float bv = bias[col];
#pragma unroll
        for (int i = 0; i < 4; ++i) {
            const int row = m0 + wm * 64 + i * 16 + rl;
            float* po = out + (size_t)row * Ndim + col;
#pragma unroll
            for (int q = 0; q < 4; ++q) {
                const float r = acc[i][j][q] + bv;
                po[(size_t)q * Ndim] = r > 0.f ? r : 0.f;
            }
        }
    }
}

// ---------------------------------------------------------------------------
// fp32 fallback path (tiny ws)
// ---------------------------------------------------------------------------
__global__ void __launch_bounds__(256) rownorm_only_kernel(const float* __restrict__ x,
                                                           float* __restrict__ invn)
{
    const int row = blockIdx.x;
    const int t = threadIdx.x;
    const float4* xr = (const float4*)(x + (size_t)row * Kdim);
    float s = 0.f;
#pragma unroll
    for (int i = 0; i < 4; ++i) {
        const float4 v = xr[i * 256 + t];
        s += v.x * v.x + v.y * v.y + v.z * v.z + v.w * v.w;
    }
#pragma unroll
    for (int off = 32; off > 0; off >>= 1) s += __shfl_down(s, off, 64);
    __shared__ float red[4];
    if ((t & 63) == 0) red[t >> 6] = s;
    __syncthreads();
    if (t == 0) {
        const float tot = red[0] + red[1] + red[2] + red[3];
        invn[row] = 1.f / (sqrtf(tot) + 1e-8f);
    }
}

__global__ void __launch_bounds__(256) fallback_gemm_kernel(
        const float* __restrict__ x, const float* __restrict__ W,
        const float* __restrict__ b, const float* __restrict__ invn,
        float* __restrict__ out)
{
    __shared__ float At[16][17], Bt[16][17];
    const int tx = threadIdx.x & 15, ty = threadIdx.x >> 4;
    const int m = blockIdx.y * 16 + ty;
    const int n = blockIdx.x * 16 + tx;
    float s = 0.f;
    for (int k0 = 0; k0 < Kdim; k0 += 16) {
        At[ty][tx] = x[(size_t)m * Kdim + k0 + tx];
        Bt[ty][tx] = W[(size_t)(blockIdx.x * 16 + ty) * Kdim + k0 + tx];
        __syncthreads();
#pragma unroll
        for (int kk = 0; kk < 16; ++kk) s += At[ty][kk] * Bt[tx][kk];
        __syncthreads();
    }
    s = s * invn[m] + b[n];
    out[(size_t)m * Ndim + n] = s > 0.f ? s : 0.f;
}

// ---------------------------------------------------------------------------
extern "C" void kernel_launch(void* const* d_in, const int* in_sizes, int n_in,
                              void* d_out, int out_size, void* d_ws, size_t ws_size,
                              hipStream_t stream)
{
    (void)in_sizes; (void)n_in; (void)out_size;
    const float* x = (const float*)d_in[0];
    const float* W = (const float*)d_in[1];
    const float* b = (const float*)d_in[2];
    float* out = (float*)d_out;

    const size_t needA = (size_t)Mdim * Kdim * sizeof(__hip_bfloat16);   // 64 MB
    const size_t needW = (size_t)Ndim * Kdim * sizeof(__hip_bfloat16);   // 32 MB

    if (ws_size >= needA + needW) {
        __hip_bfloat16* Xn = (__hip_bfloat16*)d_ws;
        __hip_bfloat16* Wb = (__hip_bfloat16*)((char*)d_ws + needA);
        preproc_kernel<<<Mdim, 256, 0, stream>>>(x, W, Xn, Wb);

        hipError_t e = hipFuncSetAttribute((const void*)gemm256_8p,
                                           hipFuncAttributeMaxDynamicSharedMemorySize,
                                           131072);
        if (e == hipSuccess) {
            gemm256_8p<<<(Mdim / 256) * (Ndim / 256), 512, 131072, stream>>>(Xn, Wb, b, out);
        } else {
            gemm_bias_relu_kernel<<<(Mdim / 128) * (Ndim / 128), 256, 0, stream>>>(Xn, Wb, b, out);
        }
    } else {
        float* invn = (float*)d_ws;
        rownorm_only_kernel<<<Mdim, 256, 0, stream>>>(x, invn);
        dim3 g(Ndim / 16, Mdim / 16);
        fallback_gemm_kernel<<<g, 256, 0, stream>>>(x, W, b, invn, out);
    }
}